// Round 1
// baseline (279.134 us; speedup 1.0000x reference)
//
#include <hip/hip_runtime.h>

#define NB 4
#define NC 64
#define NW 128
#define NH 128
#define NK 9
#define NOC 64
#define EPSV 1e-5f

// ---------- Kernel: NCHW -> NHWC transpose of f ----------
__global__ __launch_bounds__(256) void k_transpose(const float* __restrict__ f,
                                                   float* __restrict__ fb) {
    int blk = blockIdx.x;            // ((b*128)+y)*2 + xt, grid = 1024
    int xt  = blk & 1;
    int y   = (blk >> 1) & (NW - 1);
    int b   = blk >> 8;
    __shared__ float tile[64][65];
    int t  = threadIdx.x;
    int x  = t & 63;
    int c0 = t >> 6;
    const float* src = f + (((size_t)b * NC) * NW + y) * NH + xt * 64;
#pragma unroll
    for (int i = 0; i < 64; i += 4) {
        tile[c0 + i][x] = src[(size_t)(c0 + i) * (NW * NH) + x];
    }
    __syncthreads();
    float* dst = fb + (((size_t)b * NW + y) * NH + xt * 64) * NC;
    int cc = t & 63;
    int x0 = t >> 6;
#pragma unroll
    for (int i = 0; i < 64; i += 4) {
        dst[(size_t)(x0 + i) * NC + cc] = tile[cc][x0 + i];
    }
}

// ---------- Kernel: repack conv_w (OC,C,K,1) -> cwT[k][c][oc]; zero stats ----------
__global__ __launch_bounds__(256) void k_prep(const float* __restrict__ cw,
                                              float* __restrict__ cwT,
                                              float* __restrict__ stats) {
    int idx = blockIdx.x * 256 + threadIdx.x;   // 36864 total (grid 144)
    int k  = idx >> 12;
    int c  = (idx >> 6) & 63;
    int oc = idx & 63;
    cwT[idx] = cw[((size_t)oc * NC + c) * NK + k];
    if (idx < 128) stats[idx] = 0.f;
}

// ---------- Kernel: offset conv (first K ch) + BN + tanh + cumsum -> y coords ----------
__global__ __launch_bounds__(256) void k_offset(
    const float* __restrict__ f, const float* __restrict__ ow,
    const float* __restrict__ ob, const float* __restrict__ bng,
    const float* __restrict__ bnb, const float* __restrict__ bnm,
    const float* __restrict__ bnv, float* __restrict__ yc)
{
    __shared__ float wl[NK * NC * 12];   // taps padded 9->12 for float4 reads
    int t = threadIdx.x;
    for (int i = t; i < NK * NC * 9; i += 256) {
        int oc_ = i / 9;
        int tap = i - oc_ * 9;
        wl[oc_ * 12 + tap] = ow[i];      // first 9 out-channels == first 9*64*9 floats
    }
    __syncthreads();
    int blk = blockIdx.x;                // grid = B*W/2 = 256
    int b = blk >> 6;
    int w = ((blk & 63) << 1) | (t >> 7);
    int h = t & 127;
    float acc[NK];
#pragma unroll
    for (int k = 0; k < NK; ++k) acc[k] = 0.f;
    const float* fbase = f + (size_t)b * NC * NW * NH;
    for (int c = 0; c < NC; ++c) {
        const float* fc = fbase + (size_t)c * (NW * NH);
        float v[9];
#pragma unroll
        for (int dy = 0; dy < 3; ++dy) {
            int yy = w + dy - 1;
            bool yok = (yy >= 0) && (yy < NW);
#pragma unroll
            for (int dx = 0; dx < 3; ++dx) {
                int xx = h + dx - 1;
                bool ok = yok && (xx >= 0) && (xx < NH);
                v[dy * 3 + dx] = ok ? fc[yy * NH + xx] : 0.f;
            }
        }
#pragma unroll
        for (int k = 0; k < NK; ++k) {
            const float* wp = &wl[(k * NC + c) * 12];
            float4 wa = *(const float4*)wp;
            float4 wb = *(const float4*)(wp + 4);
            float w8 = wp[8];
            acc[k] += v[0] * wa.x + v[1] * wa.y + v[2] * wa.z + v[3] * wa.w
                    + v[4] * wb.x + v[5] * wb.y + v[6] * wb.z + v[7] * wb.w
                    + v[8] * w8;
        }
    }
    float tk[NK];
#pragma unroll
    for (int k = 0; k < NK; ++k) {
        float zz = acc[k] + ob[k];
        zz = (zz - bnm[k]) * rsqrtf(bnv[k] + EPSV);
        zz = zz * bng[k] + bnb[k];
        tk[k] = tanhf(zz);
    }
    // exact reference cumsum: new[4]=0; 5..7 cumulative; 8 and 0 stay raw
    float nw_[NK];
    nw_[4] = 0.f;
    nw_[5] = tk[5];
    nw_[6] = nw_[5] + tk[6];
    nw_[7] = nw_[6] + tk[7];
    nw_[8] = tk[8];
    nw_[3] = tk[3];
    nw_[2] = nw_[3] + tk[2];
    nw_[1] = nw_[2] + tk[1];
    nw_[0] = tk[0];
#pragma unroll
    for (int k = 0; k < NK; ++k)
        yc[(((size_t)b * NK + k) * NW + w) * NH + h] = (float)w + nw_[k];
}

// ---------- Kernel: bilinear sample + (C*K x OC) GEMM + GN partial stats ----------
__global__ __launch_bounds__(128) void k_main(
    const float* __restrict__ fb, const float* __restrict__ yc,
    const float* __restrict__ cwT, const float* __restrict__ cb,
    float* __restrict__ z, float* __restrict__ stats)
{
    __shared__ float A[NC][NW];      // [c][px]  32 KB
    __shared__ float Wl[NC][NOC];    // [c][oc]  16 KB
    __shared__ float redS[16];
    __shared__ float redQ[16];
    int blk = blockIdx.x;            // b*128 + w ; grid = 512
    int w = blk & 127;
    int b = blk >> 7;
    int t = threadIdx.x;
    int pxg = t & 15;                // 16 groups of 8 px
    int ocg = t >> 4;                // 8 groups of 8 oc
    float acc[8][8];
#pragma unroll
    for (int i = 0; i < 8; ++i)
#pragma unroll
        for (int j = 0; j < 8; ++j) acc[i][j] = 0.f;

    for (int k = 0; k < NK; ++k) {
        __syncthreads();
        // stage conv weights slice k: cwT[k][c][oc] contiguous
        {
            const float4* srcW = (const float4*)(cwT + (size_t)k * (NC * NOC));
            float4* dstW = (float4*)Wl;
            for (int i = t; i < (NC * NOC) / 4; i += 128) dstW[i] = srcW[i];
        }
        // bilinear sample: each thread = one px (h), all 64 channels
        {
            int h = t;
            float ys = yc[(((size_t)b * NK + k) * NW + w) * NH + h];
            float xs = (float)h + (-5.0f + 1.125f * (float)k);
            int y0 = (int)floorf(ys);
            y0 = min(max(y0, 0), NW - 1);
            int y1 = min(y0 + 1, NW - 1);
            int x0 = (int)floorf(xs);
            x0 = min(max(x0, 0), NH - 1);
            int x1 = min(x0 + 1, NH - 1);
            float wy0 = (float)y1 - ys;
            float wy1 = ys - (float)y0;
            float wx0 = (float)x1 - xs;
            float wx1 = xs - (float)x0;
            float w00 = wy0 * wx0, w01 = wy0 * wx1;
            float w10 = wy1 * wx0, w11 = wy1 * wx1;
            const float* r00 = fb + (((size_t)b * NW + y0) * NH + x0) * NC;
            const float* r01 = fb + (((size_t)b * NW + y0) * NH + x1) * NC;
            const float* r10 = fb + (((size_t)b * NW + y1) * NH + x0) * NC;
            const float* r11 = fb + (((size_t)b * NW + y1) * NH + x1) * NC;
#pragma unroll
            for (int i = 0; i < 16; ++i) {
                float4 v00 = *(const float4*)(r00 + i * 4);
                float4 v01 = *(const float4*)(r01 + i * 4);
                float4 v10 = *(const float4*)(r10 + i * 4);
                float4 v11 = *(const float4*)(r11 + i * 4);
                A[i * 4 + 0][h] = v00.x * w00 + v01.x * w01 + v10.x * w10 + v11.x * w11;
                A[i * 4 + 1][h] = v00.y * w00 + v01.y * w01 + v10.y * w10 + v11.y * w11;
                A[i * 4 + 2][h] = v00.z * w00 + v01.z * w01 + v10.z * w10 + v11.z * w11;
                A[i * 4 + 3][h] = v00.w * w00 + v01.w * w01 + v10.w * w10 + v11.w * w11;
            }
        }
        __syncthreads();
        // register-tiled GEMM: acc[8px][8oc] += A[c][px] * Wl[c][oc]
#pragma unroll 8
        for (int c = 0; c < NC; ++c) {
            float4 a0 = *(const float4*)&A[c][pxg * 8];
            float4 a1 = *(const float4*)&A[c][pxg * 8 + 4];
            float4 w0 = *(const float4*)&Wl[c][ocg * 8];
            float4 w1 = *(const float4*)&Wl[c][ocg * 8 + 4];
            float av[8] = {a0.x, a0.y, a0.z, a0.w, a1.x, a1.y, a1.z, a1.w};
            float wv[8] = {w0.x, w0.y, w0.z, w0.w, w1.x, w1.y, w1.z, w1.w};
#pragma unroll
            for (int i = 0; i < 8; ++i)
#pragma unroll
                for (int j = 0; j < 8; ++j)
                    acc[i][j] += av[i] * wv[j];
        }
    }

    // epilogue: + bias, write z, per-group partial sums
    float bias[8];
#pragma unroll
    for (int j = 0; j < 8; ++j) bias[j] = cb[ocg * 8 + j];
    float s0 = 0.f, q0 = 0.f, s1 = 0.f, q1 = 0.f;
#pragma unroll
    for (int j = 0; j < 8; ++j) {
        int oc = ocg * 8 + j;
        float* zp = z + (((size_t)b * NOC + oc) * NW + w) * NH + pxg * 8;
        float vv[8];
#pragma unroll
        for (int i = 0; i < 8; ++i) {
            float v = acc[i][j] + bias[j];
            vv[i] = v;
            if (j < 4) { s0 += v; q0 += v * v; }
            else       { s1 += v; q1 += v * v; }
        }
        *(float4*)zp       = make_float4(vv[0], vv[1], vv[2], vv[3]);
        *(float4*)(zp + 4) = make_float4(vv[4], vv[5], vv[6], vv[7]);
    }
    if (t < 16) { redS[t] = 0.f; redQ[t] = 0.f; }
    __syncthreads();
    int g0 = ocg * 2, g1 = ocg * 2 + 1;
    atomicAdd(&redS[g0], s0); atomicAdd(&redQ[g0], q0);
    atomicAdd(&redS[g1], s1); atomicAdd(&redQ[g1], q1);
    __syncthreads();
    if (t < 16) {
        atomicAdd(&stats[((size_t)b * 16 + t) * 2 + 0], redS[t]);
        atomicAdd(&stats[((size_t)b * 16 + t) * 2 + 1], redQ[t]);
    }
}

// ---------- Kernel: GroupNorm finalize + affine + ReLU ----------
__global__ __launch_bounds__(256) void k_gn(const float* __restrict__ z,
                                            const float* __restrict__ stats,
                                            const float* __restrict__ gg,
                                            const float* __restrict__ gb,
                                            float* __restrict__ out) {
    int idx = blockIdx.x * 256 + threadIdx.x;   // grid 4096 -> 1,048,576 float4s
    size_t base = (size_t)idx * 4;
    int oc = (int)((base >> 14) & 63);
    int b  = (int)(base >> 20);
    int g  = oc >> 2;
    float sm = stats[((size_t)b * 16 + g) * 2 + 0];
    float sq = stats[((size_t)b * 16 + g) * 2 + 1];
    const float cnt = 65536.f;                  // 4 ch * 128 * 128
    float mu  = sm / cnt;
    float var = sq / cnt - mu * mu;
    float inv = rsqrtf(var + EPSV);
    float gam = gg[oc] * inv;
    float bet = gb[oc] - mu * gam;
    float4 v = *(const float4*)(z + base);
    v.x = fmaxf(v.x * gam + bet, 0.f);
    v.y = fmaxf(v.y * gam + bet, 0.f);
    v.z = fmaxf(v.z * gam + bet, 0.f);
    v.w = fmaxf(v.w * gam + bet, 0.f);
    *(float4*)(out + base) = v;
}

extern "C" void kernel_launch(void* const* d_in, const int* in_sizes, int n_in,
                              void* d_out, int out_size, void* d_ws, size_t ws_size,
                              hipStream_t stream) {
    const float* f   = (const float*)d_in[0];
    const float* ow  = (const float*)d_in[1];
    const float* ob  = (const float*)d_in[2];
    const float* bng = (const float*)d_in[3];
    const float* bnb = (const float*)d_in[4];
    const float* bnm = (const float*)d_in[5];
    const float* bnv = (const float*)d_in[6];
    const float* cw  = (const float*)d_in[7];
    const float* cb  = (const float*)d_in[8];
    const float* gg  = (const float*)d_in[9];
    const float* gb  = (const float*)d_in[10];

    float* ws  = (float*)d_ws;
    float* fb  = ws;                       // 4,194,304 floats (NHWC f)
    float* yc  = fb + 4194304;             //   589,824 floats (y coords)
    float* cwT = yc + 589824;              //    36,864 floats (repacked conv_w)
    float* z   = cwT + 36864;              // 4,194,304 floats (conv out)
    float* st  = z + 4194304;              //       128 floats (GN stats)

    k_prep<<<144, 256, 0, stream>>>(cw, cwT, st);
    k_transpose<<<1024, 256, 0, stream>>>(f, fb);
    k_offset<<<256, 256, 0, stream>>>(f, ow, ob, bng, bnb, bnm, bnv, yc);
    k_main<<<512, 128, 0, stream>>>(fb, yc, cwT, cb, z, st);
    k_gn<<<4096, 256, 0, stream>>>(z, st, gg, gb, (float*)d_out);
}

// Round 2
// 211.849 us; speedup vs baseline: 1.3176x; 1.3176x over previous
//
#include <hip/hip_runtime.h>

#define NB 4
#define NC 64
#define NW 128
#define NH 128
#define NK 9
#define NOC 64
#define EPSV 1e-5f

// ---------- NCHW -> NHWC transpose of f ----------
__global__ __launch_bounds__(256) void k_transpose(const float* __restrict__ f,
                                                   float* __restrict__ fb) {
    int blk = blockIdx.x;            // ((b*128)+y)*2 + xt, grid = 1024
    int xt  = blk & 1;
    int y   = (blk >> 1) & (NW - 1);
    int b   = blk >> 8;
    __shared__ float tile[64][65];
    int t  = threadIdx.x;
    int x  = t & 63;
    int c0 = t >> 6;
    const float* src = f + (((size_t)b * NC) * NW + y) * NH + xt * 64;
#pragma unroll
    for (int i = 0; i < 64; i += 4) {
        tile[c0 + i][x] = src[(size_t)(c0 + i) * (NW * NH) + x];
    }
    __syncthreads();
    float* dst = fb + (((size_t)b * NW + y) * NH + xt * 64) * NC;
    int cc = t & 63;
    int x0 = t >> 6;
#pragma unroll
    for (int i = 0; i < 64; i += 4) {
        dst[(size_t)(x0 + i) * NC + cc] = tile[cc][x0 + i];
    }
}

// ---------- repack conv_w (OC,C,K,1) -> cwT[k][c][oc]; zero stats ----------
__global__ __launch_bounds__(256) void k_prep(const float* __restrict__ cw,
                                              float* __restrict__ cwT,
                                              float* __restrict__ stats) {
    int idx = blockIdx.x * 256 + threadIdx.x;   // 36864 total (grid 144)
    int k  = idx >> 12;
    int c  = (idx >> 6) & 63;
    int oc = idx & 63;
    cwT[idx] = cw[((size_t)oc * NC + c) * NK + k];
    if (idx < 128) stats[idx] = 0.f;
}

// ---------- offset conv partials: block = (b, w, c-quarter) ----------
__global__ __launch_bounds__(128) void k_off1(const float* __restrict__ f,
                                              const float* __restrict__ ow,
                                              float* __restrict__ offp) {
    int blk = blockIdx.x;            // grid = 4*128*4 = 2048
    int cq = blk & 3;
    int w  = (blk >> 2) & 127;
    int b  = blk >> 9;
    int c0 = cq << 4;
    __shared__ float wl[NK * 16 * 12];
    int t = threadIdx.x;             // 128
    for (int i = t; i < NK * 16 * 9; i += 128) {
        int kc  = i / 9;             // k*16 + ci
        int tap = i - kc * 9;
        int k   = kc >> 4;
        int ci  = kc & 15;
        wl[kc * 12 + tap] = ow[((size_t)(k * 64 + c0 + ci)) * 9 + tap];
    }
    __syncthreads();
    int h = t;
    float acc[NK];
#pragma unroll
    for (int k = 0; k < NK; ++k) acc[k] = 0.f;
    const float* fbase = f + (((size_t)b * 64 + c0) << 14);
    for (int ci = 0; ci < 16; ++ci) {
        const float* fc = fbase + ((size_t)ci << 14);
        float v[9];
#pragma unroll
        for (int dy = 0; dy < 3; ++dy) {
            int yy = w + dy - 1;
            bool yok = (unsigned)yy < 128u;
#pragma unroll
            for (int dx = 0; dx < 3; ++dx) {
                int xx = h + dx - 1;
                v[dy * 3 + dx] = (yok && ((unsigned)xx < 128u)) ? fc[(yy << 7) + xx] : 0.f;
            }
        }
#pragma unroll
        for (int k = 0; k < NK; ++k) {
            const float* wp = &wl[(k * 16 + ci) * 12];
            float4 wa = *(const float4*)wp;
            float4 wb = *(const float4*)(wp + 4);
            acc[k] += v[0] * wa.x + v[1] * wa.y + v[2] * wa.z + v[3] * wa.w
                    + v[4] * wb.x + v[5] * wb.y + v[6] * wb.z + v[7] * wb.w
                    + v[8] * wp[8];
        }
    }
#pragma unroll
    for (int k = 0; k < NK; ++k)
        offp[(((size_t)cq * 36 + b * 9 + k) << 14) + (w << 7) + h] = acc[k];
}

// ---------- sum partials + bias + BN + tanh + cumsum -> y coords ----------
__global__ __launch_bounds__(256) void k_off2(const float* __restrict__ offp,
                                              const float* __restrict__ ob,
                                              const float* __restrict__ bng,
                                              const float* __restrict__ bnb,
                                              const float* __restrict__ bnm,
                                              const float* __restrict__ bnv,
                                              float* __restrict__ yc) {
    int idx = blockIdx.x * 256 + threadIdx.x;   // 65536 (grid 256)
    int b = idx >> 14;
    int rest = idx & 16383;
    int w = rest >> 7;
    float tk[NK];
#pragma unroll
    for (int k = 0; k < NK; ++k) {
        int o = (((b * 9 + k)) << 14) + rest;
        float zz = offp[o] + offp[o + 589824] + offp[o + 2 * 589824] + offp[o + 3 * 589824];
        zz += ob[k];
        zz = (zz - bnm[k]) * rsqrtf(bnv[k] + EPSV);
        zz = zz * bng[k] + bnb[k];
        tk[k] = tanhf(zz);
    }
    float nw_[NK];
    nw_[4] = 0.f;
    nw_[5] = tk[5];
    nw_[6] = nw_[5] + tk[6];
    nw_[7] = nw_[6] + tk[7];
    nw_[8] = tk[8];
    nw_[3] = tk[3];
    nw_[2] = nw_[3] + tk[2];
    nw_[1] = nw_[2] + tk[1];
    nw_[0] = tk[0];
#pragma unroll
    for (int k = 0; k < NK; ++k)
        yc[((b * 9 + k) << 14) + rest] = (float)w + nw_[k];
}

// ---------- bilinear sample + (C*K x OC) GEMM + GN partial stats ----------
__global__ __launch_bounds__(256) void k_main(
    const float* __restrict__ fb, const float* __restrict__ yc,
    const float* __restrict__ cwT, const float* __restrict__ cb,
    float* __restrict__ z, float* __restrict__ stats)
{
    __shared__ float A[64 * 64];     // [px][c] swizzled cols, 16 KB
    __shared__ float Wl[64 * 64];    // [c][oc], 16 KB
    __shared__ float redS[16];
    __shared__ float redQ[16];
    int j = blockIdx.x;              // grid = 1024, chunked XCD swizzle
    int orig = ((j & 7) << 7) | (j >> 3);
    int hh = orig & 1;
    int w  = (orig >> 1) & 127;
    int b  = orig >> 8;
    int t = threadIdx.x;
    // sampling roles
    int c4 = t & 15;                 // channel-float4 index
    int pq = t >> 4;                 // px = pq + 16*s
    // gemm roles
    int pg = t & 15;                 // px = pg + 16*i
    int og = t >> 4;                 // oc = og*4 + j  (== GN group og)
    float acc[4][4];
#pragma unroll
    for (int i = 0; i < 4; ++i)
#pragma unroll
        for (int jj = 0; jj < 4; ++jj) acc[i][jj] = 0.f;

    for (int k = 0; k < NK; ++k) {
        __syncthreads();
        // stage W slice k (cwT[k][c][oc], 16 KB)
        {
            const float4* srcW = (const float4*)(cwT + (size_t)k * 4096);
            float4* dstW = (float4*)Wl;
#pragma unroll
            for (int i = 0; i < 4; ++i) dstW[t + 256 * i] = srcW[t + 256 * i];
        }
        // bilinear sample 64 px x 64 c, coalesced: wave = 4 rows x 16 c-float4
        float xoff = -5.0f + 1.125f * (float)k;
#pragma unroll
        for (int s = 0; s < 4; ++s) {
            int px = pq + (s << 4);
            int h = (hh << 6) + px;
            float ys = yc[((b * 9 + k) << 14) + (w << 7) + h];
            float xs = (float)h + xoff;
            int y0 = (int)floorf(ys);
            y0 = min(max(y0, 0), 127);
            int y1 = min(y0 + 1, 127);
            int x0 = (int)floorf(xs);
            x0 = min(max(x0, 0), 127);
            int x1 = min(x0 + 1, 127);
            float wy0 = (float)y1 - ys;
            float wy1 = ys - (float)y0;
            float wx0 = (float)x1 - xs;
            float wx1 = xs - (float)x0;
            float w00 = wy0 * wx0, w01 = wy0 * wx1;
            float w10 = wy1 * wx0, w11 = wy1 * wx1;
            int r0 = ((((b << 7) + y0) << 7) + x0) << 6;
            int r1 = ((((b << 7) + y0) << 7) + x1) << 6;
            int r2 = ((((b << 7) + y1) << 7) + x0) << 6;
            int r3 = ((((b << 7) + y1) << 7) + x1) << 6;
            float4 v00 = *(const float4*)(fb + r0 + (c4 << 2));
            float4 v01 = *(const float4*)(fb + r1 + (c4 << 2));
            float4 v10 = *(const float4*)(fb + r2 + (c4 << 2));
            float4 v11 = *(const float4*)(fb + r3 + (c4 << 2));
            float4 a;
            a.x = v00.x * w00 + v01.x * w01 + v10.x * w10 + v11.x * w11;
            a.y = v00.y * w00 + v01.y * w01 + v10.y * w10 + v11.y * w11;
            a.z = v00.z * w00 + v01.z * w01 + v10.z * w10 + v11.z * w11;
            a.w = v00.w * w00 + v01.w * w01 + v10.w * w10 + v11.w * w11;
            int col = (c4 << 2) ^ ((px & 7) << 2);
            *(float4*)&A[(px << 6) + col] = a;
        }
        __syncthreads();
        // register-tiled GEMM: acc[4px][4oc] += A[px][c] * Wl[c][oc]
#pragma unroll
        for (int c = 0; c < 64; c += 4) {
            int swz = c ^ ((pg & 7) << 2);
            float4 a0 = *(const float4*)&A[((pg +  0) << 6) + swz];
            float4 a1 = *(const float4*)&A[((pg + 16) << 6) + swz];
            float4 a2 = *(const float4*)&A[((pg + 32) << 6) + swz];
            float4 a3 = *(const float4*)&A[((pg + 48) << 6) + swz];
            float4 w0 = *(const float4*)&Wl[((c + 0) << 6) + (og << 2)];
            float4 w1 = *(const float4*)&Wl[((c + 1) << 6) + (og << 2)];
            float4 w2 = *(const float4*)&Wl[((c + 2) << 6) + (og << 2)];
            float4 w3 = *(const float4*)&Wl[((c + 3) << 6) + (og << 2)];
            float av[4][4] = {{a0.x, a0.y, a0.z, a0.w},
                              {a1.x, a1.y, a1.z, a1.w},
                              {a2.x, a2.y, a2.z, a2.w},
                              {a3.x, a3.y, a3.z, a3.w}};
            float wv[4][4] = {{w0.x, w0.y, w0.z, w0.w},
                              {w1.x, w1.y, w1.z, w1.w},
                              {w2.x, w2.y, w2.z, w2.w},
                              {w3.x, w3.y, w3.z, w3.w}};
#pragma unroll
            for (int cc = 0; cc < 4; ++cc)
#pragma unroll
                for (int i = 0; i < 4; ++i)
#pragma unroll
                    for (int jj = 0; jj < 4; ++jj)
                        acc[i][jj] += av[i][cc] * wv[cc][jj];
        }
    }

    // epilogue: + bias, write z (NCHW), per-group stats (group == og)
    float4 bias4 = *(const float4*)(cb + (og << 2));
    float bb[4] = {bias4.x, bias4.y, bias4.z, bias4.w};
    float s = 0.f, q = 0.f;
#pragma unroll
    for (int i = 0; i < 4; ++i) {
        int h = (hh << 6) + pg + (i << 4);
#pragma unroll
        for (int jj = 0; jj < 4; ++jj) {
            float v = acc[i][jj] + bb[jj];
            z[(((b << 6) + (og << 2) + jj) << 14) + (w << 7) + h] = v;
            s += v;
            q += v * v;
        }
    }
    if (t < 16) { redS[t] = 0.f; redQ[t] = 0.f; }
    __syncthreads();
    atomicAdd(&redS[og], s);
    atomicAdd(&redQ[og], q);
    __syncthreads();
    if (t < 16) {
        atomicAdd(&stats[(((size_t)b << 4) + t) * 2 + 0], redS[t]);
        atomicAdd(&stats[(((size_t)b << 4) + t) * 2 + 1], redQ[t]);
    }
}

// ---------- GroupNorm finalize + affine + ReLU ----------
__global__ __launch_bounds__(256) void k_gn(const float* __restrict__ z,
                                            const float* __restrict__ stats,
                                            const float* __restrict__ gg,
                                            const float* __restrict__ gb,
                                            float* __restrict__ out) {
    int idx = blockIdx.x * 256 + threadIdx.x;   // grid 4096
    size_t base = (size_t)idx * 4;
    int oc = (int)((base >> 14) & 63);
    int b  = (int)(base >> 20);
    int g  = oc >> 2;
    float sm = stats[((size_t)b * 16 + g) * 2 + 0];
    float sq = stats[((size_t)b * 16 + g) * 2 + 1];
    const float cnt = 65536.f;
    float mu  = sm / cnt;
    float var = sq / cnt - mu * mu;
    float inv = rsqrtf(var + EPSV);
    float gam = gg[oc] * inv;
    float bet = gb[oc] - mu * gam;
    float4 v = *(const float4*)(z + base);
    v.x = fmaxf(v.x * gam + bet, 0.f);
    v.y = fmaxf(v.y * gam + bet, 0.f);
    v.z = fmaxf(v.z * gam + bet, 0.f);
    v.w = fmaxf(v.w * gam + bet, 0.f);
    *(float4*)(out + base) = v;
}

extern "C" void kernel_launch(void* const* d_in, const int* in_sizes, int n_in,
                              void* d_out, int out_size, void* d_ws, size_t ws_size,
                              hipStream_t stream) {
    const float* f   = (const float*)d_in[0];
    const float* ow  = (const float*)d_in[1];
    const float* ob  = (const float*)d_in[2];
    const float* bng = (const float*)d_in[3];
    const float* bnb = (const float*)d_in[4];
    const float* bnm = (const float*)d_in[5];
    const float* bnv = (const float*)d_in[6];
    const float* cw  = (const float*)d_in[7];
    const float* cb  = (const float*)d_in[8];
    const float* gg  = (const float*)d_in[9];
    const float* gb  = (const float*)d_in[10];

    float* ws   = (float*)d_ws;
    float* fb   = ws;                      // 4,194,304
    float* yc   = fb + 4194304;            //   589,824
    float* cwT  = yc + 589824;             //    36,864
    float* z    = cwT + 36864;             // 4,194,304
    float* st   = z + 4194304;             //       128
    float* offp = st + 128;                // 2,359,296 (4 partials)

    k_prep<<<144, 256, 0, stream>>>(cw, cwT, st);
    k_transpose<<<1024, 256, 0, stream>>>(f, fb);
    k_off1<<<2048, 128, 0, stream>>>(f, ow, offp);
    k_off2<<<256, 256, 0, stream>>>(offp, ob, bng, bnb, bnm, bnv, yc);
    k_main<<<1024, 256, 0, stream>>>(fb, yc, cwT, cb, z, st);
    k_gn<<<4096, 256, 0, stream>>>(z, st, gg, gb, (float*)d_out);
}

// Round 4
// 179.729 us; speedup vs baseline: 1.5531x; 1.1787x over previous
//
#include <hip/hip_runtime.h>
#include <hip/hip_bf16.h>

#define EPSV 1e-5f

typedef __attribute__((ext_vector_type(8))) short short8;
typedef __attribute__((ext_vector_type(4))) float f32x4;

// ---------- NCHW fp32 -> NHWC bf16 transpose of f ----------
__global__ __launch_bounds__(256) void k_transpose(const float* __restrict__ f,
                                                   ushort* __restrict__ fbh) {
    int blk = blockIdx.x;            // ((b*128)+y)*2 + xt, grid = 1024
    int xt  = blk & 1;
    int y   = (blk >> 1) & 127;
    int b   = blk >> 8;
    __shared__ float tile[64][65];
    int t  = threadIdx.x;
    int x  = t & 63;
    int c0 = t >> 6;
    const float* src = f + (((size_t)b * 64) * 128 + y) * 128 + xt * 64;
#pragma unroll
    for (int i = 0; i < 64; i += 4) {
        tile[c0 + i][x] = src[(size_t)(c0 + i) * (128 * 128) + x];
    }
    __syncthreads();
    ushort* dst = fbh + (((size_t)b * 128 + y) * 128 + xt * 64) * 64;
    int cc = t & 63;
    int x0 = t >> 6;
#pragma unroll
    for (int i = 0; i < 64; i += 4) {
        dst[(size_t)(x0 + i) * 64 + cc] =
            __bfloat16_as_ushort(__float2bfloat16(tile[cc][x0 + i]));
    }
}

// ---------- pack conv_w into MFMA B-fragment order (bf16); zero stats ----------
// frag fi = (k*2+kk)*4 + ot ; lane l, j:  W[c = kk*32+(l>>4)*8+j][oc = ot*16+(l&15)]
__global__ __launch_bounds__(256) void k_prep(const float* __restrict__ cw,
                                              ushort* __restrict__ wpk,
                                              float* __restrict__ stats) {
    int idx = blockIdx.x * 256 + threadIdx.x;   // 36864 total (grid 144)
    int j  = idx & 7;
    int l  = (idx >> 3) & 63;
    int ot = (idx >> 9) & 3;
    int kk = (idx >> 11) & 1;
    int k  = idx >> 12;
    int c  = kk * 32 + ((l >> 4) << 3) + j;
    int oc = (ot << 4) + (l & 15);
    float v = cw[((size_t)oc * 64 + c) * 9 + k];
    wpk[idx] = __bfloat16_as_ushort(__float2bfloat16(v));
    if (idx < 128) stats[idx] = 0.f;
}

// ---------- offset conv partials: block = (b, w, c-quarter) ----------
__global__ __launch_bounds__(128) void k_off1(const float* __restrict__ f,
                                              const float* __restrict__ ow,
                                              float* __restrict__ offp) {
    int blk = blockIdx.x;            // grid = 4*128*4 = 2048
    int cq = blk & 3;
    int w  = (blk >> 2) & 127;
    int b  = blk >> 9;
    int c0 = cq << 4;
    __shared__ float wl[9 * 16 * 12];
    int t = threadIdx.x;             // 128
    for (int i = t; i < 9 * 16 * 9; i += 128) {
        int kc  = i / 9;             // k*16 + ci
        int tap = i - kc * 9;
        int k   = kc >> 4;
        int ci  = kc & 15;
        wl[kc * 12 + tap] = ow[((size_t)(k * 64 + c0 + ci)) * 9 + tap];
    }
    __syncthreads();
    int h = t;
    float acc[9];
#pragma unroll
    for (int k = 0; k < 9; ++k) acc[k] = 0.f;
    const float* fbase = f + (((size_t)b * 64 + c0) << 14);
    for (int ci = 0; ci < 16; ++ci) {
        const float* fc = fbase + ((size_t)ci << 14);
        float v[9];
#pragma unroll
        for (int dy = 0; dy < 3; ++dy) {
            int yy = w + dy - 1;
            bool yok = (unsigned)yy < 128u;
#pragma unroll
            for (int dx = 0; dx < 3; ++dx) {
                int xx = h + dx - 1;
                v[dy * 3 + dx] = (yok && ((unsigned)xx < 128u)) ? fc[(yy << 7) + xx] : 0.f;
            }
        }
#pragma unroll
        for (int k = 0; k < 9; ++k) {
            const float* wp = &wl[(k * 16 + ci) * 12];
            float4 wa = *(const float4*)wp;
            float4 wb = *(const float4*)(wp + 4);
            acc[k] += v[0] * wa.x + v[1] * wa.y + v[2] * wa.z + v[3] * wa.w
                    + v[4] * wb.x + v[5] * wb.y + v[6] * wb.z + v[7] * wb.w
                    + v[8] * wp[8];
        }
    }
#pragma unroll
    for (int k = 0; k < 9; ++k)
        offp[(((size_t)cq * 36 + b * 9 + k) << 14) + (w << 7) + h] = acc[k];
}

// ---------- sum partials + bias + BN + tanh + cumsum -> y coords ----------
__global__ __launch_bounds__(256) void k_off2(const float* __restrict__ offp,
                                              const float* __restrict__ ob,
                                              const float* __restrict__ bng,
                                              const float* __restrict__ bnb,
                                              const float* __restrict__ bnm,
                                              const float* __restrict__ bnv,
                                              float* __restrict__ yc) {
    int idx = blockIdx.x * 256 + threadIdx.x;   // 65536 (grid 256)
    int b = idx >> 14;
    int rest = idx & 16383;
    int w = rest >> 7;
    float tk[9];
#pragma unroll
    for (int k = 0; k < 9; ++k) {
        int o = ((b * 9 + k) << 14) + rest;
        float zz = offp[o] + offp[o + 589824] + offp[o + 2 * 589824] + offp[o + 3 * 589824];
        zz += ob[k];
        zz = (zz - bnm[k]) * rsqrtf(bnv[k] + EPSV);
        zz = zz * bng[k] + bnb[k];
        tk[k] = tanhf(zz);
    }
    float nw_[9];
    nw_[4] = 0.f;
    nw_[5] = tk[5];
    nw_[6] = nw_[5] + tk[6];
    nw_[7] = nw_[6] + tk[7];
    nw_[8] = tk[8];
    nw_[3] = tk[3];
    nw_[2] = nw_[3] + tk[2];
    nw_[1] = nw_[2] + tk[1];
    nw_[0] = tk[0];
#pragma unroll
    for (int k = 0; k < 9; ++k)
        yc[((b * 9 + k) << 14) + rest] = (float)w + nw_[k];
}

// ---------- bilinear sample (bf16) + MFMA GEMM + GN partial stats ----------
// block: 32 px (h = hq*32..), 64 oc; 4 waves: m = wid&1 (px half), n = wid>>1 (oc half)
__global__ __launch_bounds__(256) void k_main(
    const ushort* __restrict__ fbh, const float* __restrict__ yc,
    const ushort* __restrict__ wpk, const float* __restrict__ cb,
    float* __restrict__ z, float* __restrict__ stats)
{
    __shared__ union {
        struct {
            ushort A[32 * 64];          // bf16 [px][c], XOR-swizzled, 4 KB
            float  tup[9][32][8];       // r00,r01,r10,r11 (byte offs), w00,w01,w10,w11
        } p;
        float Z2[32 * 65];              // epilogue transpose
    } sm;
    __shared__ float redS[16];
    __shared__ float redQ[16];

    int jb = blockIdx.x;                // grid 2048, chunked XCD swizzle
    int orig = (jb & 7) * 256 + (jb >> 3);
    int hq = orig & 3;
    int w  = (orig >> 2) & 127;
    int b  = orig >> 9;
    int t    = threadIdx.x;
    int lane = t & 63;
    int wid  = t >> 6;
    int m = wid & 1;
    int n = wid >> 1;

    // ---- tuple phase: per (k,px) sample geometry, computed once ----
    for (int i = t; i < 288; i += 256) {
        int k  = i >> 5;
        int px = i & 31;
        int h  = (hq << 5) + px;
        float ys = yc[((b * 9 + k) << 14) + (w << 7) + h];
        float xs = (float)h + (-5.0f + 1.125f * (float)k);
        int y0 = min(max((int)floorf(ys), 0), 127);
        int y1 = min(y0 + 1, 127);
        int x0 = min(max((int)floorf(xs), 0), 127);
        int x1 = min(x0 + 1, 127);
        float wy0 = (float)y1 - ys, wy1 = ys - (float)y0;
        float wx0 = (float)x1 - xs, wx1 = xs - (float)x0;
        float* tp = sm.p.tup[k][px];
        tp[0] = __int_as_float(((((b << 7) + y0) << 7) + x0) << 7);
        tp[1] = __int_as_float(((((b << 7) + y0) << 7) + x1) << 7);
        tp[2] = __int_as_float(((((b << 7) + y1) << 7) + x0) << 7);
        tp[3] = __int_as_float(((((b << 7) + y1) << 7) + x1) << 7);
        tp[4] = wy0 * wx0;
        tp[5] = wy0 * wx1;
        tp[6] = wy1 * wx0;
        tp[7] = wy1 * wx1;
    }
    __syncthreads();

    f32x4 acc0 = {0.f, 0.f, 0.f, 0.f};
    f32x4 acc1 = {0.f, 0.f, 0.f, 0.f};
    const char* fp = (const char*)fbh;
    char* Ab = (char*)sm.p.A;
    int cg = t & 15;                    // 8-byte chunk (4 bf16 channels)
    int pq = t >> 4;
    int cgo = cg << 3;
    const short8* wp8 = (const short8*)wpk;

    for (int k = 0; k < 9; ++k) {
        // B-fragments straight from global (L1-hot, fragment-packed)
        int fb0 = ((k * 2) * 4 + (n << 1)) * 64 + lane;
        short8 wf00 = wp8[fb0];
        short8 wf01 = wp8[fb0 + 64];
        short8 wf10 = wp8[fb0 + 256];
        short8 wf11 = wp8[fb0 + 320];

        // sampling: 2 px per thread, 4 channels each
#pragma unroll
        for (int s = 0; s < 2; ++s) {
            int px = pq + (s << 4);
            const float* tp = sm.p.tup[k][px];
            float4 tr = *(const float4*)tp;
            float4 tw = *(const float4*)(tp + 4);
            uint2 u00 = *(const uint2*)(fp + __float_as_int(tr.x) + cgo);
            uint2 u01 = *(const uint2*)(fp + __float_as_int(tr.y) + cgo);
            uint2 u10 = *(const uint2*)(fp + __float_as_int(tr.z) + cgo);
            uint2 u11 = *(const uint2*)(fp + __float_as_int(tr.w) + cgo);
            float a0 = __uint_as_float(u00.x << 16) * tw.x + __uint_as_float(u01.x << 16) * tw.y
                     + __uint_as_float(u10.x << 16) * tw.z + __uint_as_float(u11.x << 16) * tw.w;
            float a1 = __uint_as_float(u00.x & 0xffff0000u) * tw.x + __uint_as_float(u01.x & 0xffff0000u) * tw.y
                     + __uint_as_float(u10.x & 0xffff0000u) * tw.z + __uint_as_float(u11.x & 0xffff0000u) * tw.w;
            float a2 = __uint_as_float(u00.y << 16) * tw.x + __uint_as_float(u01.y << 16) * tw.y
                     + __uint_as_float(u10.y << 16) * tw.z + __uint_as_float(u11.y << 16) * tw.w;
            float a3 = __uint_as_float(u00.y & 0xffff0000u) * tw.x + __uint_as_float(u01.y & 0xffff0000u) * tw.y
                     + __uint_as_float(u10.y & 0xffff0000u) * tw.z + __uint_as_float(u11.y & 0xffff0000u) * tw.w;
            uint2 pk;
            pk.x = (uint)__bfloat16_as_ushort(__float2bfloat16(a0))
                 | ((uint)__bfloat16_as_ushort(__float2bfloat16(a1)) << 16);
            pk.y = (uint)__bfloat16_as_ushort(__float2bfloat16(a2))
                 | ((uint)__bfloat16_as_ushort(__float2bfloat16(a3)) << 16);
            int wb = (px << 7) + (cgo ^ ((px & 7) << 4));
            *(uint2*)(Ab + wb) = pk;
        }
        __syncthreads();

        // MFMA: A-frags from swizzled LDS
        {
            int row = (m << 4) + (lane & 15);
            int rb0 = (row << 7) + ((((lane >> 4) << 4)) ^ ((lane & 7) << 4));
            short8 af0 = *(const short8*)(Ab + rb0);
            short8 af1 = *(const short8*)(Ab + (rb0 ^ 64));
            acc0 = __builtin_amdgcn_mfma_f32_16x16x32_bf16(af0, wf00, acc0, 0, 0, 0);
            acc0 = __builtin_amdgcn_mfma_f32_16x16x32_bf16(af1, wf10, acc0, 0, 0, 0);
            acc1 = __builtin_amdgcn_mfma_f32_16x16x32_bf16(af0, wf01, acc1, 0, 0, 0);
            acc1 = __builtin_amdgcn_mfma_f32_16x16x32_bf16(af1, wf11, acc1, 0, 0, 0);
        }
        __syncthreads();
    }

    // ---- epilogue: bias, stats, LDS transpose, coalesced NCHW z writes ----
    int lane15 = lane & 15;
    float b0 = cb[(n << 5) + lane15];
    float b1 = cb[(n << 5) + 16 + lane15];
    float v00 = acc0.x + b0, v01 = acc0.y + b0, v02 = acc0.z + b0, v03 = acc0.w + b0;
    float v10 = acc1.x + b1, v11 = acc1.y + b1, v12 = acc1.z + b1, v13 = acc1.w + b1;
    float s0 = v00 + v01 + v02 + v03;
    float q0 = v00 * v00 + v01 * v01 + v02 * v02 + v03 * v03;
    float s1 = v10 + v11 + v12 + v13;
    float q1 = v10 * v10 + v11 * v11 + v12 * v12 + v13 * v13;
    if (t < 16) { redS[t] = 0.f; redQ[t] = 0.f; }
    __syncthreads();
    int g0 = (n << 3) + (lane15 >> 2);
    atomicAdd(&redS[g0], s0);     atomicAdd(&redQ[g0], q0);
    atomicAdd(&redS[g0 + 4], s1); atomicAdd(&redQ[g0 + 4], q1);
    int pxb = (m << 4) + ((lane >> 4) << 2);
    int ocb = (n << 5) + lane15;
    sm.Z2[(pxb + 0) * 65 + ocb] = v00;
    sm.Z2[(pxb + 1) * 65 + ocb] = v01;
    sm.Z2[(pxb + 2) * 65 + ocb] = v02;
    sm.Z2[(pxb + 3) * 65 + ocb] = v03;
    sm.Z2[(pxb + 0) * 65 + ocb + 16] = v10;
    sm.Z2[(pxb + 1) * 65 + ocb + 16] = v11;
    sm.Z2[(pxb + 2) * 65 + ocb + 16] = v12;
    sm.Z2[(pxb + 3) * 65 + ocb + 16] = v13;
    __syncthreads();
    if (t < 16) {
        atomicAdd(&stats[((size_t)b * 16 + t) * 2 + 0], redS[t]);
        atomicAdd(&stats[((size_t)b * 16 + t) * 2 + 1], redQ[t]);
    }
    int oc = t >> 2, part = t & 3;
    float4 o0, o1;
    o0.x = sm.Z2[(part * 8 + 0) * 65 + oc];
    o0.y = sm.Z2[(part * 8 + 1) * 65 + oc];
    o0.z = sm.Z2[(part * 8 + 2) * 65 + oc];
    o0.w = sm.Z2[(part * 8 + 3) * 65 + oc];
    o1.x = sm.Z2[(part * 8 + 4) * 65 + oc];
    o1.y = sm.Z2[(part * 8 + 5) * 65 + oc];
    o1.z = sm.Z2[(part * 8 + 6) * 65 + oc];
    o1.w = sm.Z2[(part * 8 + 7) * 65 + oc];
    float* zp = z + (((size_t)(b << 6) + oc) << 14) + (w << 7) + (hq << 5) + part * 8;
    *(float4*)zp = o0;
    *(float4*)(zp + 4) = o1;
}

// ---------- GroupNorm finalize + affine + ReLU ----------
__global__ __launch_bounds__(256) void k_gn(const float* __restrict__ z,
                                            const float* __restrict__ stats,
                                            const float* __restrict__ gg,
                                            const float* __restrict__ gb,
                                            float* __restrict__ out) {
    int idx = blockIdx.x * 256 + threadIdx.x;   // grid 4096
    size_t base = (size_t)idx * 4;
    int oc = (int)((base >> 14) & 63);
    int b  = (int)(base >> 20);
    int g  = oc >> 2;
    float sm = stats[((size_t)b * 16 + g) * 2 + 0];
    float sq = stats[((size_t)b * 16 + g) * 2 + 1];
    const float cnt = 65536.f;
    float mu  = sm / cnt;
    float var = sq / cnt - mu * mu;
    float inv = rsqrtf(var + EPSV);
    float gam = gg[oc] * inv;
    float bet = gb[oc] - mu * gam;
    float4 v = *(const float4*)(z + base);
    v.x = fmaxf(v.x * gam + bet, 0.f);
    v.y = fmaxf(v.y * gam + bet, 0.f);
    v.z = fmaxf(v.z * gam + bet, 0.f);
    v.w = fmaxf(v.w * gam + bet, 0.f);
    *(float4*)(out + base) = v;
}

extern "C" void kernel_launch(void* const* d_in, const int* in_sizes, int n_in,
                              void* d_out, int out_size, void* d_ws, size_t ws_size,
                              hipStream_t stream) {
    const float* f   = (const float*)d_in[0];
    const float* ow  = (const float*)d_in[1];
    const float* ob  = (const float*)d_in[2];
    const float* bng = (const float*)d_in[3];
    const float* bnb = (const float*)d_in[4];
    const float* bnm = (const float*)d_in[5];
    const float* bnv = (const float*)d_in[6];
    const float* cw  = (const float*)d_in[7];
    const float* cb  = (const float*)d_in[8];
    const float* gg  = (const float*)d_in[9];
    const float* gb  = (const float*)d_in[10];

    char* wsb = (char*)d_ws;
    ushort* fbh = (ushort*)wsb;                          // 8 MB  (bf16 NHWC f)
    float*  yc  = (float*)(wsb + 8388608);               // 2,359,296 B
    ushort* wpk = (ushort*)(wsb + 10747904);             //    73,728 B
    float*  z   = (float*)(wsb + 10821632);              // 16 MB
    float*  st  = (float*)(wsb + 27598848);              //       512 B
    float*  offp= (float*)(wsb + 27599360);              // 9,437,184 B

    k_prep<<<144, 256, 0, stream>>>(cw, wpk, st);
    k_transpose<<<1024, 256, 0, stream>>>(f, fbh);
    k_off1<<<2048, 128, 0, stream>>>(f, ow, offp);
    k_off2<<<256, 256, 0, stream>>>(offp, ob, bng, bnb, bnm, bnv, yc);
    k_main<<<2048, 256, 0, stream>>>(fbh, yc, wpk, cb, z, st);
    k_gn<<<4096, 256, 0, stream>>>(z, st, gg, gb, (float*)d_out);
}

// Round 6
// 158.229 us; speedup vs baseline: 1.7641x; 1.1359x over previous
//
#include <hip/hip_runtime.h>
#include <hip/hip_bf16.h>

#define EPSV 1e-5f

typedef __attribute__((ext_vector_type(8))) short short8;
typedef __attribute__((ext_vector_type(4))) float f32x4;

__device__ __forceinline__ uint2 bilerp_pack(uint2 u00, uint2 u01, uint2 u10, uint2 u11, float4 tw) {
    float a0 = __uint_as_float(u00.x << 16) * tw.x + __uint_as_float(u01.x << 16) * tw.y
             + __uint_as_float(u10.x << 16) * tw.z + __uint_as_float(u11.x << 16) * tw.w;
    float a1 = __uint_as_float(u00.x & 0xffff0000u) * tw.x + __uint_as_float(u01.x & 0xffff0000u) * tw.y
             + __uint_as_float(u10.x & 0xffff0000u) * tw.z + __uint_as_float(u11.x & 0xffff0000u) * tw.w;
    float a2 = __uint_as_float(u00.y << 16) * tw.x + __uint_as_float(u01.y << 16) * tw.y
             + __uint_as_float(u10.y << 16) * tw.z + __uint_as_float(u11.y << 16) * tw.w;
    float a3 = __uint_as_float(u00.y & 0xffff0000u) * tw.x + __uint_as_float(u01.y & 0xffff0000u) * tw.y
             + __uint_as_float(u10.y & 0xffff0000u) * tw.z + __uint_as_float(u11.y & 0xffff0000u) * tw.w;
    uint2 pk;
    pk.x = (uint)__bfloat16_as_ushort(__float2bfloat16(a0))
         | ((uint)__bfloat16_as_ushort(__float2bfloat16(a1)) << 16);
    pk.y = (uint)__bfloat16_as_ushort(__float2bfloat16(a2))
         | ((uint)__bfloat16_as_ushort(__float2bfloat16(a3)) << 16);
    return pk;
}

// ---------- k_pre: transpose (bf16 hi+lo NHWC) + pack conv_w + pack offset_w hi/lo + zero stats ----------
__global__ __launch_bounds__(256) void k_pre(const float* __restrict__ f,
                                             const float* __restrict__ cw,
                                             const float* __restrict__ ow,
                                             ushort* __restrict__ fbh,
                                             ushort* __restrict__ flo,
                                             ushort* __restrict__ wpk,
                                             ushort* __restrict__ wpk2,
                                             float* __restrict__ stats) {
    int blk = blockIdx.x;
    int t = threadIdx.x;
    if (blk < 1024) {
        __shared__ float tile[64][65];
        int xt = blk & 1;
        int y  = (blk >> 1) & 127;
        int b  = blk >> 8;
        int x = t & 63, c0 = t >> 6;
        const float* src = f + (((size_t)b * 64) * 128 + y) * 128 + xt * 64;
#pragma unroll
        for (int i = 0; i < 64; i += 4)
            tile[c0 + i][x] = src[(size_t)(c0 + i) * 16384 + x];
        __syncthreads();
        size_t dbase = (((size_t)b * 128 + y) * 128 + xt * 64) * 64;
        int cc = t & 63, x0 = t >> 6;
#pragma unroll
        for (int i = 0; i < 64; i += 4) {
            float v = tile[cc][x0 + i];
            ushort hi = __bfloat16_as_ushort(__float2bfloat16(v));
            float vhi = __uint_as_float((uint)hi << 16);
            ushort lo = __bfloat16_as_ushort(__float2bfloat16(v - vhi));
            fbh[dbase + (size_t)(x0 + i) * 64 + cc] = hi;
            flo[dbase + (size_t)(x0 + i) * 64 + cc] = lo;
        }
    } else if (blk < 1168) {
        // conv_w -> MFMA B-frags: frag fi=(k*2+kk)*4+ot; lane l,j: W[c=kk*32+(l>>4)*8+j][oc=ot*16+(l&15)]
        int idx = (blk - 1024) * 256 + t;   // 36864
        int j  = idx & 7;
        int l  = (idx >> 3) & 63;
        int ot = (idx >> 9) & 3;
        int kk = (idx >> 11) & 1;
        int k  = idx >> 12;
        int c  = kk * 32 + ((l >> 4) << 3) + j;
        int oc = (ot << 4) + (l & 15);
        wpk[idx] = __bfloat16_as_ushort(__float2bfloat16(cw[((size_t)oc * 64 + c) * 9 + k]));
        if (idx < 128) stats[idx] = 0.f;
    } else {
        // offset_w -> MFMA B-frags hi/lo: frag fi=tap*2+kk; lane l,j: W2[c=kk*32+(l>>4)*8+j][n=l&15] (n<9)
        int idx = (blk - 1168) * 256 + t;   // 9216
        int j   = idx & 7;
        int l   = (idx >> 3) & 63;
        int kk  = (idx >> 9) & 1;
        int tap = idx >> 10;
        int c   = kk * 32 + ((l >> 4) << 3) + j;
        int n   = l & 15;
        float v = (n < 9) ? ow[((size_t)n * 64 + c) * 9 + tap] : 0.f;
        ushort hi = __bfloat16_as_ushort(__float2bfloat16(v));
        float vhi = __uint_as_float((uint)hi << 16);
        ushort lo = __bfloat16_as_ushort(__float2bfloat16(v - vhi));
        wpk2[idx] = hi;
        wpk2[idx + 9216] = lo;
    }
}

// ---------- k_fused: split-bf16 offset-conv MFMA + BN/tanh/cumsum + bilinear sample + main MFMA + GN stats ----------
__global__ __launch_bounds__(256) void k_fused(
    const ushort* __restrict__ fbh,
    const ushort* __restrict__ flo,
    const ushort* __restrict__ wpk,
    const ushort* __restrict__ wpk2,
    const float* __restrict__ ob, const float* __restrict__ bng,
    const float* __restrict__ bnb, const float* __restrict__ bnm,
    const float* __restrict__ bnv, const float* __restrict__ cb,
    float* __restrict__ z, float* __restrict__ stats)
{
    __shared__ struct {
        ushort AH[2][2048];       // 2 x 4KB hi tiles, XOR-swizzled [32px][64c] bf16
        ushort AL[2][2048];       // 2 x 4KB lo tiles (phase 0 only)
        float  tup[9][32][8];     // per (k,px): 4 row-byte-offsets + 4 bilerp weights
        float  cs[32][12];        // phase-0 conv out [px][k]
    } smx;
    __shared__ float redS[16], redQ[16];

    int jb = blockIdx.x;                 // grid 2048, chunked XCD swizzle
    int orig = (jb & 7) * 256 + (jb >> 3);
    int hq = orig & 3;
    int w  = (orig >> 2) & 127;
    int b  = orig >> 9;
    int t    = threadIdx.x;
    int lane = t & 63;
    int wid  = t >> 6;
    int m = wid & 1;
    int n = wid >> 1;

    const char* fpH = (const char*)fbh;
    const char* fpL = (const char*)flo;
    int cg  = t & 15;                    // 8-byte chunk (4 bf16 channels)
    int pq  = t >> 4;                    // px = pq, pq+16
    int cgo = cg << 3;

    // fragment addressing (shared by both phases)
    int frow = (m << 4) + (lane & 15);
    int frb0 = (frow << 7) + (((lane >> 4) << 4) ^ ((lane & 7) << 4));

    // ================= phase 0: offset conv via split-bf16 MFMA =================
    f32x4 acc0k = {0.f, 0.f, 0.f, 0.f};
    const short8* wp2 = (const short8*)wpk2;

    // prologue: stage tap 0 (dy=0, dx=0)
    {
        int ysrc = w - 1;
        bool rok = (unsigned)ysrc < 128u;
        char* AbH = (char*)smx.AH[0];
        char* AbL = (char*)smx.AL[0];
#pragma unroll
        for (int s = 0; s < 2; ++s) {
            int px = pq + (s << 4);
            int xsrc = (hq << 5) + px - 1;
            uint2 vh = make_uint2(0u, 0u), vl = make_uint2(0u, 0u);
            if (rok && ((unsigned)xsrc < 128u)) {
                int off = ((((((b << 7) + ysrc) << 7) + xsrc)) << 7) + cgo;
                vh = *(const uint2*)(fpH + off);
                vl = *(const uint2*)(fpL + off);
            }
            int wb = (px << 7) + (cgo ^ ((px & 7) << 4));
            *(uint2*)(AbH + wb) = vh;
            *(uint2*)(AbL + wb) = vl;
        }
    }
    for (int tap = 0; tap < 9; ++tap) {
        __syncthreads();
        int cur = tap & 1;
        // load tap+1 (early issue)
        uint2 gh[2] = {make_uint2(0u, 0u), make_uint2(0u, 0u)};
        uint2 gl[2] = {make_uint2(0u, 0u), make_uint2(0u, 0u)};
        if (tap < 8) {
            int tn = tap + 1;
            int dy = tn / 3;
            int dx = tn - dy * 3;
            int ysrc = w + dy - 1;
            bool rok = (unsigned)ysrc < 128u;
#pragma unroll
            for (int s = 0; s < 2; ++s) {
                int px = pq + (s << 4);
                int xsrc = (hq << 5) + px + dx - 1;
                if (rok && ((unsigned)xsrc < 128u)) {
                    int off = ((((((b << 7) + ysrc) << 7) + xsrc)) << 7) + cgo;
                    gh[s] = *(const uint2*)(fpH + off);
                    gl[s] = *(const uint2*)(fpL + off);
                }
            }
        }
        // split-bf16 MFMA on buf[cur] (waves 0,1; m == wid)
        if (wid < 2) {
            const char* ArH = (const char*)smx.AH[cur];
            const char* ArL = (const char*)smx.AL[cur];
            short8 ah0 = *(const short8*)(ArH + frb0);
            short8 ah1 = *(const short8*)(ArH + (frb0 ^ 64));
            short8 al0 = *(const short8*)(ArL + frb0);
            short8 al1 = *(const short8*)(ArL + (frb0 ^ 64));
            short8 wh0 = wp2[(tap * 2 + 0) * 64 + lane];
            short8 wh1 = wp2[(tap * 2 + 1) * 64 + lane];
            short8 wl0 = wp2[1152 + (tap * 2 + 0) * 64 + lane];
            short8 wl1 = wp2[1152 + (tap * 2 + 1) * 64 + lane];
            acc0k = __builtin_amdgcn_mfma_f32_16x16x32_bf16(ah0, wh0, acc0k, 0, 0, 0);
            acc0k = __builtin_amdgcn_mfma_f32_16x16x32_bf16(al0, wh0, acc0k, 0, 0, 0);
            acc0k = __builtin_amdgcn_mfma_f32_16x16x32_bf16(ah0, wl0, acc0k, 0, 0, 0);
            acc0k = __builtin_amdgcn_mfma_f32_16x16x32_bf16(ah1, wh1, acc0k, 0, 0, 0);
            acc0k = __builtin_amdgcn_mfma_f32_16x16x32_bf16(al1, wh1, acc0k, 0, 0, 0);
            acc0k = __builtin_amdgcn_mfma_f32_16x16x32_bf16(ah1, wl1, acc0k, 0, 0, 0);
        }
        // store tap+1 (write-late)
        if (tap < 8) {
            char* AbH = (char*)smx.AH[cur ^ 1];
            char* AbL = (char*)smx.AL[cur ^ 1];
#pragma unroll
            for (int s = 0; s < 2; ++s) {
                int px = pq + (s << 4);
                int wb = (px << 7) + (cgo ^ ((px & 7) << 4));
                *(uint2*)(AbH + wb) = gh[s];
                *(uint2*)(AbL + wb) = gl[s];
            }
        }
    }
    // write conv result to cs[px][k]
    if (wid < 2) {
#pragma unroll
        for (int r = 0; r < 4; ++r) {
            int pxo = (m << 4) + ((lane >> 4) << 2) + r;
            int ko = lane & 15;
            if (ko < 9) smx.cs[pxo][ko] = acc0k[r];
        }
    }
    __syncthreads();
    // finalize: BN + tanh + cumsum + sample geometry -> tup
    if (t < 32) {
        float tk[9];
#pragma unroll
        for (int k = 0; k < 9; ++k) {
            float zz = smx.cs[t][k] + ob[k];
            zz = (zz - bnm[k]) * rsqrtf(bnv[k] + EPSV);
            zz = zz * bng[k] + bnb[k];
            tk[k] = tanhf(zz);
        }
        float nw_[9];
        nw_[4] = 0.f;
        nw_[5] = tk[5];
        nw_[6] = nw_[5] + tk[6];
        nw_[7] = nw_[6] + tk[7];
        nw_[8] = tk[8];
        nw_[3] = tk[3];
        nw_[2] = nw_[3] + tk[2];
        nw_[1] = nw_[2] + tk[1];
        nw_[0] = tk[0];
        int h = (hq << 5) + t;
#pragma unroll
        for (int k = 0; k < 9; ++k) {
            float ys = (float)w + nw_[k];
            float xs = (float)h + (-5.0f + 1.125f * (float)k);
            int y0 = min(max((int)floorf(ys), 0), 127);
            int y1 = min(y0 + 1, 127);
            int x0 = min(max((int)floorf(xs), 0), 127);
            int x1 = min(x0 + 1, 127);
            float wy0 = (float)y1 - ys, wy1 = ys - (float)y0;
            float wx0 = (float)x1 - xs, wx1 = xs - (float)x0;
            float* tp = smx.tup[k][t];
            tp[0] = __int_as_float(((((b << 7) + y0) << 7) + x0) << 7);
            tp[1] = __int_as_float(((((b << 7) + y0) << 7) + x1) << 7);
            tp[2] = __int_as_float(((((b << 7) + y1) << 7) + x0) << 7);
            tp[3] = __int_as_float(((((b << 7) + y1) << 7) + x1) << 7);
            tp[4] = wy0 * wx0;
            tp[5] = wy0 * wx1;
            tp[6] = wy1 * wx0;
            tp[7] = wy1 * wx1;
        }
    }
    __syncthreads();

    // ================= phase 1: bilinear sample + main MFMA (bf16, as R4) =================
    f32x4 acc0 = {0.f, 0.f, 0.f, 0.f};
    f32x4 acc1 = {0.f, 0.f, 0.f, 0.f};
    const short8* wp8 = (const short8*)wpk;

    // prologue: sample k=0 -> AH[0]
    {
        char* Ab = (char*)smx.AH[0];
#pragma unroll
        for (int s = 0; s < 2; ++s) {
            int px = pq + (s << 4);
            const float* tp = smx.tup[0][px];
            float4 tr = *(const float4*)tp;
            float4 tw = *(const float4*)(tp + 4);
            uint2 u00 = *(const uint2*)(fpH + __float_as_int(tr.x) + cgo);
            uint2 u01 = *(const uint2*)(fpH + __float_as_int(tr.y) + cgo);
            uint2 u10 = *(const uint2*)(fpH + __float_as_int(tr.z) + cgo);
            uint2 u11 = *(const uint2*)(fpH + __float_as_int(tr.w) + cgo);
            *(uint2*)(Ab + (px << 7) + (cgo ^ ((px & 7) << 4))) = bilerp_pack(u00, u01, u10, u11, tw);
        }
    }
    for (int k = 0; k < 9; ++k) {
        __syncthreads();
        int cur = k & 1;
        // issue gathers for k+1 (load-early)
        uint2 u[2][4];
        float4 twn[2];
        if (k < 8) {
#pragma unroll
            for (int s = 0; s < 2; ++s) {
                int px = pq + (s << 4);
                const float* tp = smx.tup[k + 1][px];
                float4 tr = *(const float4*)tp;
                twn[s] = *(const float4*)(tp + 4);
                u[s][0] = *(const uint2*)(fpH + __float_as_int(tr.x) + cgo);
                u[s][1] = *(const uint2*)(fpH + __float_as_int(tr.y) + cgo);
                u[s][2] = *(const uint2*)(fpH + __float_as_int(tr.z) + cgo);
                u[s][3] = *(const uint2*)(fpH + __float_as_int(tr.w) + cgo);
            }
        }
        // W frags + MFMA from AH[cur]
        int fb0 = (k * 8 + (n << 1)) * 64 + lane;
        short8 wf00 = wp8[fb0];
        short8 wf01 = wp8[fb0 + 64];
        short8 wf10 = wp8[fb0 + 256];
        short8 wf11 = wp8[fb0 + 320];
        const char* Ar = (const char*)smx.AH[cur];
        short8 af0 = *(const short8*)(Ar + frb0);
        short8 af1 = *(const short8*)(Ar + (frb0 ^ 64));
        acc0 = __builtin_amdgcn_mfma_f32_16x16x32_bf16(af0, wf00, acc0, 0, 0, 0);
        acc0 = __builtin_amdgcn_mfma_f32_16x16x32_bf16(af1, wf10, acc0, 0, 0, 0);
        acc1 = __builtin_amdgcn_mfma_f32_16x16x32_bf16(af0, wf01, acc1, 0, 0, 0);
        acc1 = __builtin_amdgcn_mfma_f32_16x16x32_bf16(af1, wf11, acc1, 0, 0, 0);
        // pack + store k+1 (write-late)
        if (k < 8) {
            char* Ab = (char*)smx.AH[cur ^ 1];
#pragma unroll
            for (int s = 0; s < 2; ++s) {
                int px = pq + (s << 4);
                *(uint2*)(Ab + (px << 7) + (cgo ^ ((px & 7) << 4))) =
                    bilerp_pack(u[s][0], u[s][1], u[s][2], u[s][3], twn[s]);
            }
        }
    }

    // ================= epilogue: bias, GN stats, LDS transpose, NCHW z writes =================
    float* Z2 = (float*)&smx;            // overlays AH/AL (dead now); 32*65 floats
    int lane15 = lane & 15;
    float b0 = cb[(n << 5) + lane15];
    float b1 = cb[(n << 5) + 16 + lane15];
    float v00 = acc0.x + b0, v01 = acc0.y + b0, v02 = acc0.z + b0, v03 = acc0.w + b0;
    float v10 = acc1.x + b1, v11 = acc1.y + b1, v12 = acc1.z + b1, v13 = acc1.w + b1;
    float s0 = v00 + v01 + v02 + v03;
    float q0 = v00 * v00 + v01 * v01 + v02 * v02 + v03 * v03;
    float s1 = v10 + v11 + v12 + v13;
    float q1 = v10 * v10 + v11 * v11 + v12 * v12 + v13 * v13;
    if (t < 16) { redS[t] = 0.f; redQ[t] = 0.f; }
    __syncthreads();
    int g0 = (n << 3) + (lane15 >> 2);
    atomicAdd(&redS[g0], s0);     atomicAdd(&redQ[g0], q0);
    atomicAdd(&redS[g0 + 4], s1); atomicAdd(&redQ[g0 + 4], q1);
    int pxb = (m << 4) + ((lane >> 4) << 2);
    int ocb = (n << 5) + lane15;
    Z2[(pxb + 0) * 65 + ocb] = v00;
    Z2[(pxb + 1) * 65 + ocb] = v01;
    Z2[(pxb + 2) * 65 + ocb] = v02;
    Z2[(pxb + 3) * 65 + ocb] = v03;
    Z2[(pxb + 0) * 65 + ocb + 16] = v10;
    Z2[(pxb + 1) * 65 + ocb + 16] = v11;
    Z2[(pxb + 2) * 65 + ocb + 16] = v12;
    Z2[(pxb + 3) * 65 + ocb + 16] = v13;
    __syncthreads();
    if (t < 16) {
        atomicAdd(&stats[((size_t)b * 16 + t) * 2 + 0], redS[t]);
        atomicAdd(&stats[((size_t)b * 16 + t) * 2 + 1], redQ[t]);
    }
    int oc = t >> 2, part = t & 3;
    float4 o0, o1;
    o0.x = Z2[(part * 8 + 0) * 65 + oc];
    o0.y = Z2[(part * 8 + 1) * 65 + oc];
    o0.z = Z2[(part * 8 + 2) * 65 + oc];
    o0.w = Z2[(part * 8 + 3) * 65 + oc];
    o1.x = Z2[(part * 8 + 4) * 65 + oc];
    o1.y = Z2[(part * 8 + 5) * 65 + oc];
    o1.z = Z2[(part * 8 + 6) * 65 + oc];
    o1.w = Z2[(part * 8 + 7) * 65 + oc];
    float* zp = z + (((size_t)(b << 6) + oc) << 14) + (w << 7) + (hq << 5) + part * 8;
    *(float4*)zp = o0;
    *(float4*)(zp + 4) = o1;
}

// ---------- GroupNorm finalize + affine + ReLU ----------
__global__ __launch_bounds__(256) void k_gn(const float* __restrict__ z,
                                            const float* __restrict__ stats,
                                            const float* __restrict__ gg,
                                            const float* __restrict__ gb,
                                            float* __restrict__ out) {
    int idx = blockIdx.x * 256 + threadIdx.x;   // grid 4096
    size_t base = (size_t)idx * 4;
    int oc = (int)((base >> 14) & 63);
    int b  = (int)(base >> 20);
    int g  = oc >> 2;
    float sm = stats[((size_t)b * 16 + g) * 2 + 0];
    float sq = stats[((size_t)b * 16 + g) * 2 + 1];
    const float cnt = 65536.f;
    float mu  = sm / cnt;
    float var = sq / cnt - mu * mu;
    float inv = rsqrtf(var + EPSV);
    float gam = gg[oc] * inv;
    float bet = gb[oc] - mu * gam;
    float4 v = *(const float4*)(z + base);
    v.x = fmaxf(v.x * gam + bet, 0.f);
    v.y = fmaxf(v.y * gam + bet, 0.f);
    v.z = fmaxf(v.z * gam + bet, 0.f);
    v.w = fmaxf(v.w * gam + bet, 0.f);
    *(float4*)(out + base) = v;
}

extern "C" void kernel_launch(void* const* d_in, const int* in_sizes, int n_in,
                              void* d_out, int out_size, void* d_ws, size_t ws_size,
                              hipStream_t stream) {
    const float* f   = (const float*)d_in[0];
    const float* ow  = (const float*)d_in[1];
    const float* ob  = (const float*)d_in[2];
    const float* bng = (const float*)d_in[3];
    const float* bnb = (const float*)d_in[4];
    const float* bnm = (const float*)d_in[5];
    const float* bnv = (const float*)d_in[6];
    const float* cw  = (const float*)d_in[7];
    const float* cb  = (const float*)d_in[8];
    const float* gg  = (const float*)d_in[9];
    const float* gb  = (const float*)d_in[10];

    char* wsb = (char*)d_ws;
    ushort* fbh  = (ushort*)wsb;                    // 8,388,608 B (bf16 hi, NHWC)
    ushort* flo  = (ushort*)(wsb + 8388608);        // 8,388,608 B (bf16 lo residual)
    ushort* wpk  = (ushort*)(wsb + 16777216);       //    73,728 B
    ushort* wpk2 = (ushort*)(wsb + 16850944);       //    36,864 B (hi 9216 + lo 9216 ushorts)
    float*  z    = (float*)(wsb + 16887808);        // 16,777,216 B
    float*  st   = (float*)(wsb + 33665024);        //       512 B

    k_pre<<<1204, 256, 0, stream>>>(f, cw, ow, fbh, flo, wpk, wpk2, st);
    k_fused<<<2048, 256, 0, stream>>>(fbh, flo, wpk, wpk2, ob, bng, bnb, bnm, bnv, cb, z, st);
    k_gn<<<4096, 256, 0, stream>>>(z, st, gg, gb, (float*)d_out);
}